// Round 2
// 409.083 us; speedup vs baseline: 1.0077x; 1.0077x over previous
//
#include <hip/hip_runtime.h>
#include <math.h>

typedef __bf16 bf16;
typedef bf16 bf16x8 __attribute__((ext_vector_type(8)));
typedef float f32x4 __attribute__((ext_vector_type(4)));

#define LDS_PAD 40  // 32 k-elems padded to 40 -> 80B row stride, 2-way-max bank aliasing
#define SENT 2048   // sentinel col index; v[SENT] == 0
#define LANCZOS_M 14

// ---------------- k_pre: all transposes (fp32 -> bf16, k-contig) + CSR build, ONE launch ----
__global__ __launch_bounds__(256) void k_pre(
    const float* __restrict__ Wc, const float* __restrict__ Wq, const float* __restrict__ Wk,
    const float* __restrict__ Wv, const float* __restrict__ Wo, const float* __restrict__ W1,
    const float* __restrict__ W2, const float* __restrict__ x, const float* __restrict__ adj,
    bf16* __restrict__ WcT, bf16* __restrict__ WqT, bf16* __restrict__ WkT,
    bf16* __restrict__ WvT, bf16* __restrict__ WoT, bf16* __restrict__ W1T,
    bf16* __restrict__ W2T, bf16* __restrict__ xT,
    int* __restrict__ cnt, unsigned short* __restrict__ cols)
{
    __shared__ float tile[32][33];
    int z = blockIdx.z;
    if (z == 11) {  // ---- CSR of adjacency (incl self loops), <=64/row, sentinel-padded ----
        int flat = blockIdx.y * 16 + blockIdx.x;
        if (flat >= 512) return;
        int row = flat * 4 + (threadIdx.x >> 6);
        int lane = threadIdx.x & 63;
        int base = 0;
        for (int c0 = 0; c0 < 2048; c0 += 64) {
            float a = adj[(long)row * 2048 + c0 + lane];
            unsigned long long m = __ballot(a != 0.0f);
            if (a != 0.0f) {
                int pos = base + __popcll(m & ((1ull << lane) - 1ull));
                if (pos < 64) cols[(long)row * 64 + pos] = (unsigned short)(c0 + lane);
            }
            base += __popcll(m);
        }
        int c = base < 64 ? base : 64;
        if (lane >= c) cols[(long)row * 64 + lane] = (unsigned short)SENT;
        if (lane == 0) cnt[row] = c;
        return;
    }
    const float* src; bf16* dst; int R, C;
    switch (z) {
        case 0: src = Wc; dst = WcT; R = 256; C = 256; break;
        case 1: src = Wq; dst = WqT; R = 256; C = 256; break;
        case 2: src = Wk; dst = WkT; R = 256; C = 256; break;
        case 3: src = Wv; dst = WvT; R = 256; C = 256; break;
        case 4: src = Wo; dst = WoT; R = 256; C = 256; break;
        case 5: src = W1; dst = W1T; R = 256; C = 512; break;
        case 6: src = W2; dst = W2T; R = 512; C = 256; break;
        default: {
            int b = z - 7;
            src = x + (long)b * 2048 * 256; dst = xT + (long)b * 256 * 2048;
            R = 2048; C = 256;
        }
    }
    int c0 = blockIdx.x * 32, r0 = blockIdx.y * 32;
    if (c0 >= C || r0 >= R) return;
    int tx = threadIdx.x & 31, ty = threadIdx.x >> 5;
#pragma unroll
    for (int j = 0; j < 4; ++j)
        tile[ty + 8 * j][tx] = src[(long)(r0 + ty + 8 * j) * C + c0 + tx];
    __syncthreads();
#pragma unroll
    for (int j = 0; j < 4; ++j)
        dst[(long)(c0 + ty + 8 * j) * R + r0 + tx] = (bf16)tile[tx][ty + 8 * j];
}

// ---------------- k_main: block 0 = Lanczos lambda_max; blocks 1..128 = xp0 = L@x ----------
// Lanczos (M=LANCZOS_M): 14 sparse matvecs (vs 32+1 for power iteration) build a tridiagonal
// T; wave 0 extracts lambda_max(T) by 64-lane multisection on the Sturm sequence (4 rounds,
// range/65^4 ~ 5e-6 abs). Lanczos-14 suppresses the lambda_2 component of the estimate far
// more than shifted power-32 in every gap regime, and both approach lambda_1 from below.
// GEMM:  1024 threads, 16 waves; wave w: rows (w&3)*16.., nt tiles (w>>2)*4..+4. L exact in bf16.
__global__ __launch_bounds__(1024) void k_main(
    const int* __restrict__ cnt, const unsigned short* __restrict__ cols, float* __restrict__ lamOut,
    const float* __restrict__ L, const bf16* __restrict__ xT, bf16* __restrict__ xp0)
{
    __shared__ float va[2064], vb[2064];
    __shared__ float redf[16], redf2[16];
    __shared__ int   redi[16];
    __shared__ float bcast;
    __shared__ float alphaA[LANCZOS_M], betaA[LANCZOS_M];
    __shared__ bf16 As[64 * LDS_PAD];
    __shared__ bf16 Bs[256 * LDS_PAD];

    int t = threadIdx.x;
    if (blockIdx.x != 0) {
        // ================= xp0 GEMM: out[z][m][n] = sum_k L[m][k] * xT[z][n][k] =============
        int bx = blockIdx.x - 1;
        int rowBlk = (bx & 31) * 64;
        int z = bx >> 5;
        const bf16* BT = xT + (long)z * 256 * 2048;
        int w = t >> 6, lane = t & 63;
        int q = lane >> 4, l15 = lane & 15;
        int wm = w & 3, wn = w >> 2;  // wave's row group / nt group

        f32x4 acc[4];
#pragma unroll
        for (int i = 0; i < 4; ++i) acc[i] = (f32x4){0.0f, 0.0f, 0.0f, 0.0f};

        int ar = t >> 4, ac = (t & 15) * 2;   // A: 64x32 fp32, 2 elems/thread
        int br = t >> 2, bc = (t & 3) * 8;    // B: 256x32 bf16, 8 elems/thread
        for (int kt = 0; kt < 2048; kt += 32) {
            {
                const float* p = L + (long)(rowBlk + ar) * 2048 + kt + ac;
                float2 f = *(const float2*)p;
                union { bf16 h[2]; unsigned u; } pk;
                pk.h[0] = (bf16)f.x; pk.h[1] = (bf16)f.y;
                *(unsigned*)&As[ar * LDS_PAD + ac] = pk.u;
            }
            {
                const bf16* p = BT + (long)br * 2048 + kt + bc;
                *(uint4*)&Bs[br * LDS_PAD + bc] = *(const uint4*)p;
            }
            __syncthreads();
            bf16x8 a = *(const bf16x8*)&As[(wm * 16 + l15) * LDS_PAD + q * 8];
#pragma unroll
            for (int nt = 0; nt < 4; ++nt) {
                bf16x8 b = *(const bf16x8*)&Bs[((wn * 4 + nt) * 16 + l15) * LDS_PAD + q * 8];
                acc[nt] = __builtin_amdgcn_mfma_f32_16x16x32_bf16(a, b, acc[nt], 0, 0, 0);
            }
            __syncthreads();
        }
        long zRow = (long)z * 2048 + rowBlk + wm * 16 + q * 4;
#pragma unroll
        for (int nt = 0; nt < 4; ++nt) {
            int col = (wn * 4 + nt) * 16 + l15;
#pragma unroll
            for (int r = 0; r < 4; ++r)
                xp0[(zRow + r) * 256 + col] = (bf16)acc[nt][r];
        }
        return;
    }
    // ================= Lanczos lambda_max (single block, 1024 threads) =================
    int wid = t >> 6, lane = t & 63;
    int r0 = t, r1 = t + 1024;
    int c0 = cnt[r0], c1 = cnt[r1];
    int p0 = (c0 + 7) & ~7, p1 = (c1 + 7) & ~7;

    uint4 cr0[8], cr1[8];  // register-hoisted ELL cols (always in-bounds: rows are 64-wide)
#pragma unroll
    for (int j = 0; j < 8; ++j) {
        cr0[j] = ((const uint4*)(cols + (long)r0 * 64))[j];
        cr1[j] = ((const uint4*)(cols + (long)r1 * 64))[j];
    }

    // Gershgorin upper bound for the bisection range: lam_max(L) <= 2*maxdeg (deg = cnt-1)
    int md = max(c0, c1);
#pragma unroll
    for (int off = 32; off >= 1; off >>= 1) md = max(md, __shfl_xor(md, off));
    if (lane == 0) redi[wid] = md;
    __syncthreads();
    if (t == 0) {
        int m = 0;
        for (int i = 0; i < 16; ++i) m = max(m, redi[i]);
        bcast = (float)(2 * (m - 1)) + 1.0f;
    }
    for (int i = t; i < 2048; i += 1024) {  // pseudo-random +/- init (avoid the 0-eigenvector 1)
        unsigned u = (unsigned)i * 2654435761u;
        u ^= u >> 16; u *= 2246822519u; u ^= u >> 13;
        float mag = 0.5f + (float)((u >> 9) & 1023) * (1.0f / 1024.0f);
        va[i] = (u & 1) ? mag : -mag;
    }
    if (t == 0) { va[SENT] = 0.0f; vb[SENT] = 0.0f; }
    __syncthreads();
    float hiBound = bcast;   // read before bcast is reused (barrier below orders vs t0 write)

    // normalize v1
    float d0 = va[r0], d1 = va[r1];
    float pz = d0 * d0 + d1 * d1;
#pragma unroll
    for (int off = 32; off >= 1; off >>= 1) pz += __shfl_xor(pz, off);
    if (lane == 0) redf[wid] = pz;
    __syncthreads();
    if (t == 0) { float s = 0; for (int i = 0; i < 16; ++i) s += redf[i]; bcast = s; }
    __syncthreads();
    float sc = rsqrtf(fmaxf(bcast, 1e-30f));
    d0 *= sc; d1 *= sc;
    va[r0] = d0; va[r1] = d1;
    __syncthreads();

    // Lanczos recurrence: w = L v_j - alpha_j v_j - beta_{j-1} v_{j-1}; v_{j+1} = w/beta_j.
    // (L v)_r = cnt_r * v_r - gather_sum_r   (gather includes the self loop, cnt = deg+1)
    float* cur = va; float* nxt = vb;
    float bp = 0.0f;                 // beta_{j-1}
    float p0r = 0.0f, p1r = 0.0f;    // v_{j-1} at r0, r1 (register-resident, never gathered)
    for (int it = 0; it < LANCZOS_M; ++it) {
        float sum0 = 0.0f, sum1 = 0.0f;
#pragma unroll
        for (int j = 0; j < 8; ++j)
            if (j * 8 < p0) {
                uint4 q = cr0[j];
                sum0 += cur[q.x & 0xffff] + cur[q.x >> 16] + cur[q.y & 0xffff] + cur[q.y >> 16]
                      + cur[q.z & 0xffff] + cur[q.z >> 16] + cur[q.w & 0xffff] + cur[q.w >> 16];
            }
#pragma unroll
        for (int j = 0; j < 8; ++j)
            if (j * 8 < p1) {
                uint4 q = cr1[j];
                sum1 += cur[q.x & 0xffff] + cur[q.x >> 16] + cur[q.y & 0xffff] + cur[q.y >> 16]
                      + cur[q.z & 0xffff] + cur[q.z >> 16] + cur[q.w & 0xffff] + cur[q.w >> 16];
            }
        float w0 = (float)c0 * d0 - sum0;   // (L v)_r0
        float w1 = (float)c1 * d1 - sum1;
        // alpha_j = v_j . (L v_j)
        float pa = w0 * d0 + w1 * d1;
#pragma unroll
        for (int off = 32; off >= 1; off >>= 1) pa += __shfl_xor(pa, off);
        if (lane == 0) redf[wid] = pa;
        __syncthreads();
        if (t == 0) { float s = 0; for (int i = 0; i < 16; ++i) s += redf[i]; bcast = s; alphaA[it] = s; }
        __syncthreads();
        float alpha = bcast;
        w0 -= alpha * d0 + bp * p0r;
        w1 -= alpha * d1 + bp * p1r;
        // beta_j = ||w||
        float pb = w0 * w0 + w1 * w1;
#pragma unroll
        for (int off = 32; off >= 1; off >>= 1) pb += __shfl_xor(pb, off);
        if (lane == 0) redf2[wid] = pb;
        __syncthreads();
        if (t == 0) {
            float s = 0; for (int i = 0; i < 16; ++i) s += redf2[i];
            float b = sqrtf(fmaxf(s, 1e-30f));
            bcast = b; betaA[it] = b;
        }
        __syncthreads();
        float beta = bcast;
        float invb = 1.0f / beta;
        p0r = d0; p1r = d1;
        d0 = w0 * invb; d1 = w1 * invb;
        nxt[r0] = d0; nxt[r1] = d1;
        __syncthreads();   // nxt complete before next gather; >=2 barriers since last read of nxt
        bp = beta;
        float* tmp = cur; cur = nxt; nxt = tmp;
    }

    // lambda_max(T) by 64-lane multisection on the Sturm sequence (wave 0 only).
    // count(x) = #{d_i < 0} in d_1 = a_1-x, d_i = a_i - x - b_{i-1}^2/d_{i-1} = #eigs(T) < x.
    if (t < 64) {
        float aa[LANCZOS_M], b2[LANCZOS_M];
#pragma unroll
        for (int i = 0; i < LANCZOS_M; ++i) { aa[i] = alphaA[i]; b2[i] = betaA[i] * betaA[i]; }
        float lo = 0.0f, hi = hiBound;   // T PSD (T = V^T L V, L PSD); lam_max(T) <= Gershgorin(L)
        for (int round = 0; round < 4; ++round) {
            float step = (hi - lo) * (1.0f / 65.0f);
            float xm = lo + step * (float)(lane + 1);
            float dd = aa[0] - xm;
            int neg = dd < 0.0f ? 1 : 0;
#pragma unroll
            for (int i = 1; i < LANCZOS_M; ++i) {
                float ad = fmaxf(fabsf(dd), 1e-12f);
                dd = (dd < 0.0f) ? -ad : ad;
                dd = aa[i] - xm - b2[i - 1] / dd;
                neg += dd < 0.0f ? 1 : 0;
            }
            unsigned long long mb = __ballot(neg >= LANCZOS_M);  // lanes with xm > lam_max
            if (mb == 0ull) {
                lo = lo + step * 64.0f;          // lam_max above all probes; hi unchanged
            } else {
                int fl = (int)(__ffsll((long long)mb) - 1);
                hi = lo + step * (float)(fl + 1);
                lo = lo + step * (float)fl;
            }
        }
        if (lane == 0) lamOut[0] = 0.5f * (lo + hi) + 1e-8f;
    }
}

// ---------------- bf16 MFMA GEMM, BM=64 BN=256 BK=32, fused epilogues ----------------
// out[m][n] = sum_k A[m][k] * BT[n][k]
// TA: 1 = A bf16 | 2 = A_eff = (2/lam)*A_bf16 - Aaux_f32  (the L_norm affine, deferred)
// EPI: 0 = store bf16 | 1 = +bias,LN,relu,+resid -> f32+bf16 | 2 = +bias,+resid,LN -> f32(+bf16) | 3 = +bias,gelu -> bf16
template <int TA, int EPI>
__global__ __launch_bounds__(256) void k_gemm(
    const bf16* __restrict__ A0, const float* __restrict__ Aaux, const bf16* __restrict__ BTg,
    float* __restrict__ outF, bf16* __restrict__ outB,
    const float* __restrict__ bias, const float* __restrict__ resid,
    const float* __restrict__ gam, const float* __restrict__ bet,
    const float* __restrict__ lamPtr,
    int K, long aZ, long btZ, long outZrows, int ldOut)
{
    __shared__ bf16 As[64 * LDS_PAD];
    __shared__ bf16 Bs[256 * LDS_PAD];

    int tid = threadIdx.x;
    int w = tid >> 6, lane = tid & 63;
    int q = lane >> 4, l15 = lane & 15;
    int rowBlk = blockIdx.x * 64;
    int colB = blockIdx.y * 256;
    const bf16* BT = BTg + (long)blockIdx.z * btZ + (long)blockIdx.y * 256 * (long)K;

    float s2 = 0.0f;
    if (TA == 2) s2 = 2.0f / lamPtr[0];

    f32x4 acc[16];
#pragma unroll
    for (int i = 0; i < 16; ++i) acc[i] = (f32x4){0.0f, 0.0f, 0.0f, 0.0f};

    int ar = tid >> 2, ac = (tid & 3) * 8;
    for (int kt = 0; kt < K; kt += 32) {
        {   // stage A tile 64x32
            long base = (long)(rowBlk + ar) * K + kt + ac;
            const bf16* A = A0 + (long)blockIdx.z * aZ;
            if (TA == 1) {
                *(uint4*)&As[ar * LDS_PAD + ac] = *(const uint4*)(A + base);
            } else {
                union { bf16 h[8]; uint4 u; } in; in.u = *(const uint4*)(A + base);
                float4 f0 = *(const float4*)(Aaux + base);
                float4 f1 = *(const float4*)(Aaux + base + 4);
                float xa[8] = {f0.x, f0.y, f0.z, f0.w, f1.x, f1.y, f1.z, f1.w};
                union { bf16 h[8]; uint4 u; } pk;
#pragma unroll
                for (int j = 0; j < 8; ++j) pk.h[j] = (bf16)(s2 * (float)in.h[j] - xa[j]);
                *(uint4*)&As[ar * LDS_PAD + ac] = pk.u;
            }
        }
        {   // stage BT tile 256x32
            const bf16* p = BT + (long)tid * K + kt;
            uint4 u0 = ((const uint4*)p)[0];
            uint4 u1 = ((const uint4*)p)[1];
            uint4 u2 = ((const uint4*)p)[2];
            uint4 u3 = ((const uint4*)p)[3];
            bf16* d = &Bs[tid * LDS_PAD];
            *(uint4*)(d + 0)  = u0;
            *(uint4*)(d + 8)  = u1;
            *(uint4*)(d + 16) = u2;
            *(uint4*)(d + 24) = u3;
        }
        __syncthreads();
        bf16x8 a = *(const bf16x8*)&As[(w * 16 + l15) * LDS_PAD + q * 8];
#pragma unroll
        for (int nt = 0; nt < 16; ++nt) {
            bf16x8 b = *(const bf16x8*)&Bs[(nt * 16 + l15) * LDS_PAD + q * 8];
            acc[nt] = __builtin_amdgcn_mfma_f32_16x16x32_bf16(a, b, acc[nt], 0, 0, 0);
        }
        __syncthreads();
    }

    long zRow = (long)blockIdx.z * outZrows + rowBlk + w * 16 + q * 4;  // + r

    if (EPI == 0) {
#pragma unroll
        for (int nt = 0; nt < 16; ++nt) {
            int col = colB + nt * 16 + l15;
#pragma unroll
            for (int r = 0; r < 4; ++r)
                outB[(zRow + r) * (long)ldOut + col] = (bf16)acc[nt][r];
        }
        return;
    }
    if (EPI == 3) {
#pragma unroll
        for (int nt = 0; nt < 16; ++nt) {
            int col = colB + nt * 16 + l15;
            float bi = bias[col];
#pragma unroll
            for (int r = 0; r < 4; ++r) {
                float v = acc[nt][r] + bi;
                float g = 0.5f * v * (1.0f + erff(v * 0.70710678118654752440f));
                outB[(zRow + r) * (long)ldOut + col] = (bf16)g;
            }
        }
        return;
    }
    float s[4] = {0, 0, 0, 0}, sq[4] = {0, 0, 0, 0};
#pragma unroll
    for (int nt = 0; nt < 16; ++nt) {
        int col = colB + nt * 16 + l15;
        float bi = bias[col];
#pragma unroll
        for (int r = 0; r < 4; ++r) {
            float v = acc[nt][r] + bi;
            if (EPI == 2) v += resid[(zRow + r) * 256 + col];
            acc[nt][r] = v;
            s[r] += v; sq[r] += v * v;
        }
    }
#pragma unroll
    for (int off = 1; off <= 8; off <<= 1) {
#pragma unroll
        for (int r = 0; r < 4; ++r) { s[r] += __shfl_xor(s[r], off); sq[r] += __shfl_xor(sq[r], off); }
    }
    float mean[4], rstd[4];
#pragma unroll
    for (int r = 0; r < 4; ++r) {
        mean[r] = s[r] * (1.0f / 256.0f);
        float var = sq[r] * (1.0f / 256.0f) - mean[r] * mean[r];
        rstd[r] = rsqrtf(var + 1e-5f);
    }
#pragma unroll
    for (int nt = 0; nt < 16; ++nt) {
        int col = colB + nt * 16 + l15;
        float gc = gam[col], bc2 = bet[col];
#pragma unroll
        for (int r = 0; r < 4; ++r) {
            float v = (acc[nt][r] - mean[r]) * rstd[r] * gc + bc2;
            if (EPI == 1) v = fmaxf(v, 0.0f) + resid[(zRow + r) * 256 + col];
            long oi = (zRow + r) * (long)ldOut + col;
            outF[oi] = v;
            if (outB) outB[oi] = (bf16)v;
        }
    }
}

// ---------------- sparse gather attention: block=(b,row), wave=head, lane=dim ----------------
__global__ __launch_bounds__(256) void k_attn(const bf16* __restrict__ qg, const bf16* __restrict__ kg,
                                              const bf16* __restrict__ vg, bf16* __restrict__ og,
                                              const int* __restrict__ cnt, const unsigned short* __restrict__ cols)
{
    __shared__ unsigned short sc[64];
    __shared__ float sp[4][64];
    int row = blockIdx.x;
    int b = row >> 11, i = row & 2047;
    int tid = threadIdx.x, h = tid >> 6, lane = tid & 63;
    int c = cnt[i];
    if (tid < 64) sc[tid] = cols[(long)i * 64 + tid];
    __syncthreads();
    long qoff = (long)row * 256 + h * 64 + lane;
    float qd = (float)qg[qoff];
    long kvBase = (long)b * 2048;
    for (int j = 0; j < c; ++j) {
        int col = sc[j];
        float kd = (float)kg[(kvBase + col) * 256 + h * 64 + lane];
        float p = qd * kd;
#pragma unroll
        for (int off = 32; off >= 1; off >>= 1) p += __shfl_xor(p, off);
        if (lane == 0) sp[h][j] = p * 0.125f;
    }
    __syncthreads();
    float sj = (lane < c) ? sp[h][lane] : -3.0e38f;
    float mx = sj;
#pragma unroll
    for (int off = 32; off >= 1; off >>= 1) mx = fmaxf(mx, __shfl_xor(mx, off));
    float e = (lane < c) ? __expf(sj - mx) : 0.0f;
    float ssum = e;
#pragma unroll
    for (int off = 32; off >= 1; off >>= 1) ssum += __shfl_xor(ssum, off);
    if (lane < c) sp[h][lane] = e / ssum;
    __syncthreads();
    float acc = 0.0f;
    for (int j = 0; j < c; ++j) {
        int col = sc[j];
        acc += sp[h][j] * (float)vg[(kvBase + col) * 256 + h * 64 + lane];
    }
    og[qoff] = (bf16)acc;
}

// ---------------- launcher ----------------
extern "C" void kernel_launch(void* const* d_in, const int* in_sizes, int n_in,
                              void* d_out, int out_size, void* d_ws, size_t ws_size,
                              hipStream_t stream)
{
    const float* x   = (const float*)d_in[0];
    const float* L   = (const float*)d_in[1];
    const float* adj = (const float*)d_in[2];
    const float* Wc  = (const float*)d_in[3];
    const float* bc  = (const float*)d_in[4];
    const float* g1  = (const float*)d_in[5];
    const float* be1 = (const float*)d_in[6];
    const float* Wq  = (const float*)d_in[7];
    const float* Wk  = (const float*)d_in[8];
    const float* Wv  = (const float*)d_in[9];
    const float* Wo  = (const float*)d_in[10];
    const float* bo  = (const float*)d_in[11];
    const float* g2  = (const float*)d_in[12];
    const float* be2 = (const float*)d_in[13];
    const float* W1  = (const float*)d_in[14];
    const float* b1  = (const float*)d_in[15];
    const float* W2  = (const float*)d_in[16];
    const float* b2  = (const float*)d_in[17];
    const float* g3  = (const float*)d_in[18];
    const float* be3 = (const float*)d_in[19];
    float* out = (float*)d_out;

    char* ws = (char*)d_ws;
    size_t off = 0;
    auto alloc = [&](size_t bytes) -> void* {
        void* p = ws + off;
        off = (off + bytes + 255) & ~(size_t)255;
        return p;
    };
    float* lam           = (float*)alloc(256);
    int* cnt             = (int*)alloc(2048 * 4);
    unsigned short* cols = (unsigned short*)alloc(2048 * 64 * 2);
    bf16* WcT = (bf16*)alloc(65536 * 2);
    bf16* WqT = (bf16*)alloc(65536 * 2);   // WqT,WkT,WvT contiguous (btZ = 65536)
    bf16* WkT = (bf16*)alloc(65536 * 2);
    bf16* WvT = (bf16*)alloc(65536 * 2);
    bf16* WoT = (bf16*)alloc(65536 * 2);
    bf16* W1T = (bf16*)alloc(131072 * 2);
    bf16* W2T = (bf16*)alloc(131072 * 2);
    bf16* xT  = (bf16*)alloc((size_t)4 * 256 * 2048 * 2);
    bf16* xp0 = (bf16*)alloc((size_t)8192 * 256 * 2);
    float* x1f = (float*)alloc((size_t)8192 * 256 * 4);
    bf16* x1b  = (bf16*)alloc((size_t)8192 * 256 * 2);
    bf16* qb   = (bf16*)alloc((size_t)3 * 8192 * 256 * 2);
    bf16* ob   = (bf16*)alloc((size_t)8192 * 256 * 2);
    float* x2f = (float*)alloc((size_t)8192 * 256 * 4);
    bf16* x2b  = (bf16*)alloc((size_t)8192 * 256 * 2);
    bf16* m1   = (bf16*)alloc((size_t)8192 * 512 * 2);
    (void)in_sizes; (void)n_in; (void)out_size; (void)ws_size;

    dim3 blk(256);
    // transposes + CSR, one launch
    k_pre<<<dim3(16, 64, 12), blk, 0, stream>>>(Wc, Wq, Wk, Wv, Wo, W1, W2, x, adj,
                                                WcT, WqT, WkT, WvT, WoT, W1T, W2T, xT, cnt, cols);
    // block 0: Lanczos -> lam ; blocks 1..128: xp0[b] = L @ x[b] (lam-free)
    k_main<<<dim3(129), dim3(1024), 0, stream>>>(cnt, cols, lam, L, xT, xp0);
    // x1 = relu(LN((s2*xp0 - x)@Wc + bc; g1,be1)) + x   (L_norm affine folded into A-staging)
    k_gemm<2, 1><<<dim3(128, 1, 1), blk, 0, stream>>>(
        xp0, x, WcT, x1f, x1b, bc, x, g1, be1, lam,
        256, 0L, 0L, 0L, 256);
    // q,k,v = x1 @ {Wq,Wk,Wv}
    k_gemm<1, 0><<<dim3(128, 1, 3), blk, 0, stream>>>(
        x1b, nullptr, WqT, nullptr, qb, nullptr, nullptr, nullptr, nullptr, nullptr,
        256, 0L, 65536L, 8192L, 256);
    // sparse masked attention
    bf16* kb  = qb + (size_t)8192 * 256;
    bf16* vb2 = qb + (size_t)2 * 8192 * 256;
    k_attn<<<dim3(8192), blk, 0, stream>>>(qb, kb, vb2, ob, cnt, cols);
    // x2 = LN(x1 + o@Wo + bo; g2,be2)
    k_gemm<1, 2><<<dim3(128, 1, 1), blk, 0, stream>>>(
        ob, nullptr, WoT, x2f, x2b, bo, x1f, g2, be2, nullptr,
        256, 0L, 0L, 0L, 256);
    // m1 = gelu(x2@W1 + b1)
    k_gemm<1, 3><<<dim3(128, 2, 1), blk, 0, stream>>>(
        x2b, nullptr, W1T, nullptr, m1, b1, nullptr, nullptr, nullptr, nullptr,
        256, 0L, 0L, 0L, 512);
    // out = LN(x2 + m1@W2 + b2; g3,be3)
    k_gemm<1, 2><<<dim3(128, 1, 1), blk, 0, stream>>>(
        m1, nullptr, W2T, out, nullptr, b2, x2f, g3, be3, nullptr,
        512, 0L, 0L, 0L, 256);
}

// Round 3
// 397.298 us; speedup vs baseline: 1.0376x; 1.0297x over previous
//
#include <hip/hip_runtime.h>
#include <math.h>

typedef __bf16 bf16;
typedef bf16 bf16x8 __attribute__((ext_vector_type(8)));
typedef float f32x4 __attribute__((ext_vector_type(4)));

#define LDS_PAD 40  // 32 k-elems padded to 40 -> 80B row stride, 2-way-max bank aliasing
#define SENT 2048   // sentinel col index; v[SENT] == 0
#define LANCZOS_M 14

// ---------------- k_pre: transposes (fp32 -> bf16, k-contig) + CSR + Lb=bf16(L), ONE launch
__global__ __launch_bounds__(256) void k_pre(
    const float* __restrict__ Wc, const float* __restrict__ Wq, const float* __restrict__ Wk,
    const float* __restrict__ Wv, const float* __restrict__ Wo, const float* __restrict__ W1,
    const float* __restrict__ W2, const float* __restrict__ x, const float* __restrict__ adj,
    bf16* __restrict__ WcT, bf16* __restrict__ WqT, bf16* __restrict__ WkT,
    bf16* __restrict__ WvT, bf16* __restrict__ WoT, bf16* __restrict__ W1T,
    bf16* __restrict__ W2T, bf16* __restrict__ xT,
    int* __restrict__ cnt, unsigned short* __restrict__ cols,
    const float* __restrict__ L, bf16* __restrict__ Lb)
{
    __shared__ float tile[32][33];
    int z = blockIdx.z;
    if (z == 11) {  // ---- CSR of adjacency (incl self loops), <=64/row, sentinel-padded ----
        int flat = blockIdx.y * 16 + blockIdx.x;
        if (flat >= 512) return;
        int row = flat * 4 + (threadIdx.x >> 6);
        int lane = threadIdx.x & 63;
        int base = 0;
        for (int c0 = 0; c0 < 2048; c0 += 64) {
            float a = adj[(long)row * 2048 + c0 + lane];
            unsigned long long m = __ballot(a != 0.0f);
            if (a != 0.0f) {
                int pos = base + __popcll(m & ((1ull << lane) - 1ull));
                if (pos < 64) cols[(long)row * 64 + pos] = (unsigned short)(c0 + lane);
            }
            base += __popcll(m);
        }
        int c = base < 64 ? base : 64;
        if (lane >= c) cols[(long)row * 64 + lane] = (unsigned short)SENT;
        if (lane == 0) cnt[row] = c;
        return;
    }
    if (z >= 12) {  // ---- Lb = bf16(L), no transpose (L symmetric), no LDS ----
        int colBase = (z - 12) * 512 + blockIdx.x * 32;
        int rowBase = blockIdx.y * 32;
        int tx = threadIdx.x & 31, ty = threadIdx.x >> 5;
#pragma unroll
        for (int j = 0; j < 4; ++j) {
            long idx = (long)(rowBase + ty + 8 * j) * 2048 + colBase + tx;
            Lb[idx] = (bf16)L[idx];
        }
        return;
    }
    const float* src; bf16* dst; int R, C;
    switch (z) {
        case 0: src = Wc; dst = WcT; R = 256; C = 256; break;
        case 1: src = Wq; dst = WqT; R = 256; C = 256; break;
        case 2: src = Wk; dst = WkT; R = 256; C = 256; break;
        case 3: src = Wv; dst = WvT; R = 256; C = 256; break;
        case 4: src = Wo; dst = WoT; R = 256; C = 256; break;
        case 5: src = W1; dst = W1T; R = 256; C = 512; break;
        case 6: src = W2; dst = W2T; R = 512; C = 256; break;
        default: {
            int b = z - 7;
            src = x + (long)b * 2048 * 256; dst = xT + (long)b * 256 * 2048;
            R = 2048; C = 256;
        }
    }
    int c0 = blockIdx.x * 32, r0 = blockIdx.y * 32;
    if (c0 >= C || r0 >= R) return;
    int tx = threadIdx.x & 31, ty = threadIdx.x >> 5;
#pragma unroll
    for (int j = 0; j < 4; ++j)
        tile[ty + 8 * j][tx] = src[(long)(r0 + ty + 8 * j) * C + c0 + tx];
    __syncthreads();
#pragma unroll
    for (int j = 0; j < 4; ++j)
        dst[(long)(c0 + ty + 8 * j) * R + r0 + tx] = (bf16)tile[tx][ty + 8 * j];
}

// ---------------- k_main: block 0 = Lanczos lambda_max; blocks 1..256 = split-K2 L@x ------
// GEMM: 256 blocks (full GPU), K halved per block -> half the serial latency chain; bf16 Lb
// input; 2-phase register prefetch hides global latency under MFMA; fp32 partial outputs
// (summed in the k_gemm<2,1> consumer - better precision than the old bf16 xp0).
// Lanczos: fused reduction  u = Lv - bp*vp; alpha = u.v; beta = sqrt(u.u - alpha^2)
// -> one block-reduction (3 barriers/iter instead of 5).
__global__ __launch_bounds__(1024) void k_main(
    const int* __restrict__ cnt, const unsigned short* __restrict__ cols, float* __restrict__ lamOut,
    const bf16* __restrict__ Lb, const bf16* __restrict__ xT, float* __restrict__ xp0f)
{
    __shared__ float va[2064], vb[2064];
    __shared__ float redf[16], redf2[16];
    __shared__ int   redi[16];
    __shared__ float bcast, bcast2;
    __shared__ float alphaA[LANCZOS_M], betaA[LANCZOS_M];
    __shared__ bf16 As[64 * LDS_PAD];
    __shared__ bf16 Bs[256 * LDS_PAD];

    int t = threadIdx.x;
    if (blockIdx.x != 0) {
        // ======== xp0 partial GEMM: out[ks][z][m][n] = sum_{k in half ks} Lb[m][k]*xT[z][n][k]
        int bx = blockIdx.x - 1;           // 0..255
        int rowBlk = (bx & 31) * 64;
        int z  = (bx >> 5) & 3;
        int ks = bx >> 7;                  // K-half
        long kbase = (long)ks * 1024;
        const bf16* BT = xT + (long)z * 256 * 2048;
        int w = t >> 6, lane = t & 63;
        int q = lane >> 4, l15 = lane & 15;
        int wm = w & 3, wn = w >> 2;       // wave's row group / nt group

        f32x4 acc[4];
#pragma unroll
        for (int i = 0; i < 4; ++i) acc[i] = (f32x4){0.0f, 0.0f, 0.0f, 0.0f};

        int ar = t >> 4, ac = (t & 15) * 2;   // A: 64x32 bf16, 2 elems (4B)/thread
        int br = t >> 2, bc = (t & 3) * 8;    // B: 256x32 bf16, 8 elems (16B)/thread
        const bf16* Ap = Lb + (long)(rowBlk + ar) * 2048 + kbase + ac;
        const bf16* Bp = BT + (long)br * 2048 + kbase + bc;
        unsigned rA = *(const unsigned*)Ap;   // prologue prefetch
        uint4    rB = *(const uint4*)Bp;
        for (int kt = 0; kt < 1024; kt += 32) {
            __syncthreads();                  // prior tile's readers done
            *(unsigned*)&As[ar * LDS_PAD + ac] = rA;
            *(uint4*)&Bs[br * LDS_PAD + bc] = rB;
            __syncthreads();
            if (kt + 32 < 1024) {             // issue next tile; lands during MFMA phase
                rA = *(const unsigned*)(Ap + kt + 32);
                rB = *(const uint4*)(Bp + kt + 32);
            }
            bf16x8 a = *(const bf16x8*)&As[(wm * 16 + l15) * LDS_PAD + q * 8];
#pragma unroll
            for (int nt = 0; nt < 4; ++nt) {
                bf16x8 b = *(const bf16x8*)&Bs[((wn * 4 + nt) * 16 + l15) * LDS_PAD + q * 8];
                acc[nt] = __builtin_amdgcn_mfma_f32_16x16x32_bf16(a, b, acc[nt], 0, 0, 0);
            }
        }
        long zRow = (long)ks * 8192 + (long)z * 2048 + rowBlk + wm * 16 + q * 4;
#pragma unroll
        for (int nt = 0; nt < 4; ++nt) {
            int col = (wn * 4 + nt) * 16 + l15;
#pragma unroll
            for (int r = 0; r < 4; ++r)
                xp0f[(zRow + r) * 256 + col] = acc[nt][r];
        }
        return;
    }
    // ================= Lanczos lambda_max (single block, 1024 threads) =================
    int wid = t >> 6, lane = t & 63;
    int r0 = t, r1 = t + 1024;
    int c0 = cnt[r0], c1 = cnt[r1];
    int p0 = (c0 + 7) & ~7, p1 = (c1 + 7) & ~7;

    uint4 cr0[8], cr1[8];  // register-hoisted ELL cols (always in-bounds: rows are 64-wide)
#pragma unroll
    for (int j = 0; j < 8; ++j) {
        cr0[j] = ((const uint4*)(cols + (long)r0 * 64))[j];
        cr1[j] = ((const uint4*)(cols + (long)r1 * 64))[j];
    }

    // Gershgorin upper bound for the bisection range: lam_max(L) <= 2*maxdeg (deg = cnt-1)
    int md = max(c0, c1);
#pragma unroll
    for (int off = 32; off >= 1; off >>= 1) md = max(md, __shfl_xor(md, off));
    if (lane == 0) redi[wid] = md;
    __syncthreads();
    if (t == 0) {
        int m = 0;
        for (int i = 0; i < 16; ++i) m = max(m, redi[i]);
        bcast = (float)(2 * (m - 1)) + 1.0f;
    }
    for (int i = t; i < 2048; i += 1024) {  // pseudo-random +/- init (avoid the 0-eigenvector 1)
        unsigned u = (unsigned)i * 2654435761u;
        u ^= u >> 16; u *= 2246822519u; u ^= u >> 13;
        float mag = 0.5f + (float)((u >> 9) & 1023) * (1.0f / 1024.0f);
        va[i] = (u & 1) ? mag : -mag;
    }
    if (t == 0) { va[SENT] = 0.0f; vb[SENT] = 0.0f; }
    __syncthreads();
    float hiBound = bcast;

    // normalize v1
    float d0 = va[r0], d1 = va[r1];
    float pz = d0 * d0 + d1 * d1;
#pragma unroll
    for (int off = 32; off >= 1; off >>= 1) pz += __shfl_xor(pz, off);
    if (lane == 0) redf[wid] = pz;
    __syncthreads();
    if (t == 0) { float s = 0; for (int i = 0; i < 16; ++i) s += redf[i]; bcast = s; }
    __syncthreads();
    float sc = rsqrtf(fmaxf(bcast, 1e-30f));
    d0 *= sc; d1 *= sc;
    va[r0] = d0; va[r1] = d1;
    __syncthreads();

    // Lanczos, fused reduction: u = L v - bp*v_prev; alpha = u.v (v.v_prev = 0);
    // beta^2 = ||u - alpha v||^2 = u.u - alpha^2. One block reduction per iteration.
    float* cur = va; float* nxt = vb;
    float bp = 0.0f;
    float p0r = 0.0f, p1r = 0.0f;    // v_{j-1} at r0, r1 (register-resident)
    for (int it = 0; it < LANCZOS_M; ++it) {
        float sum0 = 0.0f, sum1 = 0.0f;
#pragma unroll
        for (int j = 0; j < 8; ++j)
            if (j * 8 < p0) {
                uint4 q = cr0[j];
                sum0 += cur[q.x & 0xffff] + cur[q.x >> 16] + cur[q.y & 0xffff] + cur[q.y >> 16]
                      + cur[q.z & 0xffff] + cur[q.z >> 16] + cur[q.w & 0xffff] + cur[q.w >> 16];
            }
#pragma unroll
        for (int j = 0; j < 8; ++j)
            if (j * 8 < p1) {
                uint4 q = cr1[j];
                sum1 += cur[q.x & 0xffff] + cur[q.x >> 16] + cur[q.y & 0xffff] + cur[q.y >> 16]
                      + cur[q.z & 0xffff] + cur[q.z >> 16] + cur[q.w & 0xffff] + cur[q.w >> 16];
            }
        float u0 = (float)c0 * d0 - sum0 - bp * p0r;   // (L v)_r - bp*v_prev
        float u1 = (float)c1 * d1 - sum1 - bp * p1r;
        float puv = u0 * d0 + u1 * d1;
        float puu = u0 * u0 + u1 * u1;
#pragma unroll
        for (int off = 32; off >= 1; off >>= 1) {
            puv += __shfl_xor(puv, off);
            puu += __shfl_xor(puu, off);
        }
        if (lane == 0) { redf[wid] = puv; redf2[wid] = puu; }
        __syncthreads();
        if (t == 0) {
            float sv = 0, su = 0;
            for (int i = 0; i < 16; ++i) { sv += redf[i]; su += redf2[i]; }
            float b = sqrtf(fmaxf(su - sv * sv, 1e-24f));
            alphaA[it] = sv; betaA[it] = b;
            bcast = sv; bcast2 = b;
        }
        __syncthreads();
        float alpha = bcast, beta = bcast2;
        float invb = 1.0f / beta;
        float w0 = u0 - alpha * d0, w1 = u1 - alpha * d1;
        p0r = d0; p1r = d1;
        d0 = w0 * invb; d1 = w1 * invb;
        nxt[r0] = d0; nxt[r1] = d1;
        __syncthreads();
        bp = beta;
        float* tmp = cur; cur = nxt; nxt = tmp;
    }

    // lambda_max(T) by 64-lane multisection on the Sturm sequence (wave 0 only).
    if (t < 64) {
        float aa[LANCZOS_M], b2[LANCZOS_M];
#pragma unroll
        for (int i = 0; i < LANCZOS_M; ++i) { aa[i] = alphaA[i]; b2[i] = betaA[i] * betaA[i]; }
        float lo = 0.0f, hi = hiBound;
        for (int round = 0; round < 4; ++round) {
            float step = (hi - lo) * (1.0f / 65.0f);
            float xm = lo + step * (float)(lane + 1);
            float dd = aa[0] - xm;
            int neg = dd < 0.0f ? 1 : 0;
#pragma unroll
            for (int i = 1; i < LANCZOS_M; ++i) {
                float ad = fmaxf(fabsf(dd), 1e-12f);
                dd = (dd < 0.0f) ? -ad : ad;
                dd = aa[i] - xm - b2[i - 1] / dd;
                neg += dd < 0.0f ? 1 : 0;
            }
            unsigned long long mb = __ballot(neg >= LANCZOS_M);
            if (mb == 0ull) {
                lo = lo + step * 64.0f;
            } else {
                int fl = (int)(__ffsll((long long)mb) - 1);
                hi = lo + step * (float)(fl + 1);
                lo = lo + step * (float)fl;
            }
        }
        if (lane == 0) lamOut[0] = 0.5f * (lo + hi) + 1e-8f;
    }
}

// ---------------- bf16 MFMA GEMM, BM=64 BN=256 BK=32, fused epilogues, 2-phase prefetch ----
// out[m][n] = sum_k A[m][k] * BT[n][k]
// TA: 1 = A bf16 | 2 = A_eff = (2/lam)*(Apa+Apb) - Aaux   (fp32 split-K partials + L_norm affine)
// EPI: 0 = store bf16 | 1 = +bias,LN,relu,+resid -> f32+bf16 | 2 = +bias,+resid,LN -> f32(+bf16) | 3 = +bias,gelu -> bf16
template <int TA, int EPI>
__global__ __launch_bounds__(256) void k_gemm(
    const bf16* __restrict__ A0, const float* __restrict__ Apa, const float* __restrict__ Apb,
    const float* __restrict__ Aaux, const bf16* __restrict__ BTg,
    float* __restrict__ outF, bf16* __restrict__ outB,
    const float* __restrict__ bias, const float* __restrict__ resid,
    const float* __restrict__ gam, const float* __restrict__ bet,
    const float* __restrict__ lamPtr,
    int K, long aZ, long btZ, long outZrows, int ldOut)
{
    __shared__ bf16 As[64 * LDS_PAD];
    __shared__ bf16 Bs[256 * LDS_PAD];

    int tid = threadIdx.x;
    int w = tid >> 6, lane = tid & 63;
    int q = lane >> 4, l15 = lane & 15;
    int rowBlk = blockIdx.x * 64;
    int colB = blockIdx.y * 256;
    const bf16* BT = BTg + (long)blockIdx.z * btZ + (long)blockIdx.y * 256 * (long)K;

    float s2 = 0.0f;
    if (TA == 2) s2 = 2.0f / lamPtr[0];

    f32x4 acc[16];
#pragma unroll
    for (int i = 0; i < 16; ++i) acc[i] = (f32x4){0.0f, 0.0f, 0.0f, 0.0f};

    int ar = tid >> 2, ac = (tid & 3) * 8;
    long abase = (long)(rowBlk + ar) * K + ac;
    const bf16* A = A0 + (long)blockIdx.z * aZ;
    const bf16* Bp = BT + (long)tid * K;

    // -------- prologue prefetch (tile 0) --------
    uint4 aR;
    float4 pa0, pa1, pb0, pb1, xa0, xa1;
    uint4 bR0, bR1, bR2, bR3;
    if (TA == 1) {
        aR = *(const uint4*)(A + abase);
    } else {
        pa0 = *(const float4*)(Apa + abase);  pa1 = *(const float4*)(Apa + abase + 4);
        pb0 = *(const float4*)(Apb + abase);  pb1 = *(const float4*)(Apb + abase + 4);
        xa0 = *(const float4*)(Aaux + abase); xa1 = *(const float4*)(Aaux + abase + 4);
    }
    bR0 = ((const uint4*)Bp)[0]; bR1 = ((const uint4*)Bp)[1];
    bR2 = ((const uint4*)Bp)[2]; bR3 = ((const uint4*)Bp)[3];

    for (int kt = 0; kt < K; kt += 32) {
        __syncthreads();                    // prior tile's readers done
        if (TA == 1) {
            *(uint4*)&As[ar * LDS_PAD + ac] = aR;
        } else {
            float pa[8] = {pa0.x, pa0.y, pa0.z, pa0.w, pa1.x, pa1.y, pa1.z, pa1.w};
            float pb[8] = {pb0.x, pb0.y, pb0.z, pb0.w, pb1.x, pb1.y, pb1.z, pb1.w};
            float xa[8] = {xa0.x, xa0.y, xa0.z, xa0.w, xa1.x, xa1.y, xa1.z, xa1.w};
            union { bf16 h[8]; uint4 u; } pk;
#pragma unroll
            for (int j = 0; j < 8; ++j) pk.h[j] = (bf16)(s2 * (pa[j] + pb[j]) - xa[j]);
            *(uint4*)&As[ar * LDS_PAD + ac] = pk.u;
        }
        {
            bf16* d = &Bs[tid * LDS_PAD];
            *(uint4*)(d + 0)  = bR0;
            *(uint4*)(d + 8)  = bR1;
            *(uint4*)(d + 16) = bR2;
            *(uint4*)(d + 24) = bR3;
        }
        __syncthreads();
        if (kt + 32 < K) {                  // issue next tile; lands during MFMA phase
            long nb = abase + kt + 32;
            if (TA == 1) {
                aR = *(const uint4*)(A + nb);
            } else {
                pa0 = *(const float4*)(Apa + nb);  pa1 = *(const float4*)(Apa + nb + 4);
                pb0 = *(const float4*)(Apb + nb);  pb1 = *(const float4*)(Apb + nb + 4);
                xa0 = *(const float4*)(Aaux + nb); xa1 = *(const float4*)(Aaux + nb + 4);
            }
            const bf16* p = Bp + kt + 32;
            bR0 = ((const uint4*)p)[0]; bR1 = ((const uint4*)p)[1];
            bR2 = ((const uint4*)p)[2]; bR3 = ((const uint4*)p)[3];
        }
        bf16x8 a = *(const bf16x8*)&As[(w * 16 + l15) * LDS_PAD + q * 8];
#pragma unroll
        for (int nt = 0; nt < 16; ++nt) {
            bf16x8 b = *(const bf16x8*)&Bs[(nt * 16 + l15) * LDS_PAD + q * 8];
            acc[nt] = __builtin_amdgcn_mfma_f32_16x16x32_bf16(a, b, acc[nt], 0, 0, 0);
        }
    }

    long zRow = (long)blockIdx.z * outZrows + rowBlk + w * 16 + q * 4;  // + r

    if (EPI == 0) {
#pragma unroll
        for (int nt = 0; nt < 16; ++nt) {
            int col = colB + nt * 16 + l15;
#pragma unroll
            for (int r = 0; r < 4; ++r)
                outB[(zRow + r) * (long)ldOut + col] = (bf16)acc[nt][r];
        }
        return;
    }
    if (EPI == 3) {
#pragma unroll
        for (int nt = 0; nt < 16; ++nt) {
            int col = colB + nt * 16 + l15;
            float bi = bias[col];
#pragma unroll
            for (int r = 0; r < 4; ++r) {
                float v = acc[nt][r] + bi;
                float g = 0.5f * v * (1.0f + erff(v * 0.70710678118654752440f));
                outB[(zRow + r) * (long)ldOut + col] = (bf16)g;
            }
        }
        return;
    }
    float s[4] = {0, 0, 0, 0}, sq[4] = {0, 0, 0, 0};
#pragma unroll
    for (int nt = 0; nt < 16; ++nt) {
        int col = colB + nt * 16 + l15;
        float bi = bias[col];
#pragma unroll
        for (int r = 0; r < 4; ++r) {
            float v = acc[nt][r] + bi;
            if (EPI == 2) v += resid[(zRow + r) * 256 + col];
            acc[nt][r] = v;
            s[r] += v; sq[r] += v * v;
        }
    }
#pragma unroll
    for (int off = 1; off <= 8; off <<= 1) {
#pragma unroll
        for (int r = 0; r < 4; ++r) { s[r] += __shfl_xor(s[r], off); sq[r] += __shfl_xor(sq[r], off); }
    }
    float mean[4], rstd[4];
#pragma unroll
    for (int r = 0; r < 4; ++r) {
        mean[r] = s[r] * (1.0f / 256.0f);
        float var = sq[r] * (1.0f / 256.0f) - mean[r] * mean[r];
        rstd[r] = rsqrtf(var + 1e-5f);
    }
#pragma unroll
    for (int nt = 0; nt < 16; ++nt) {
        int col = colB + nt * 16 + l15;
        float gc = gam[col], bc2 = bet[col];
#pragma unroll
        for (int r = 0; r < 4; ++r) {
            float v = (acc[nt][r] - mean[r]) * rstd[r] * gc + bc2;
            if (EPI == 1) v = fmaxf(v, 0.0f) + resid[(zRow + r) * 256 + col];
            long oi = (zRow + r) * (long)ldOut + col;
            outF[oi] = v;
            if (outB) outB[oi] = (bf16)v;
        }
    }
}

// ---------------- sparse gather attention: block=(b,row), wave=head, lane=dim ----------------
__global__ __launch_bounds__(256) void k_attn(const bf16* __restrict__ qg, const bf16* __restrict__ kg,
                                              const bf16* __restrict__ vg, bf16* __restrict__ og,
                                              const int* __restrict__ cnt, const unsigned short* __restrict__ cols)
{
    __shared__ unsigned short sc[64];
    __shared__ float sp[4][64];
    int row = blockIdx.x;
    int b = row >> 11, i = row & 2047;
    int tid = threadIdx.x, h = tid >> 6, lane = tid & 63;
    int c = cnt[i];
    if (tid < 64) sc[tid] = cols[(long)i * 64 + tid];
    __syncthreads();
    long qoff = (long)row * 256 + h * 64 + lane;
    float qd = (float)qg[qoff];
    long kvBase = (long)b * 2048;
    for (int j = 0; j < c; ++j) {
        int col = sc[j];
        float kd = (float)kg[(kvBase + col) * 256 + h * 64 + lane];
        float p = qd * kd;
#pragma unroll
        for (int off = 32; off >= 1; off >>= 1) p += __shfl_xor(p, off);
        if (lane == 0) sp[h][j] = p * 0.125f;
    }
    __syncthreads();
    float sj = (lane < c) ? sp[h][lane] : -3.0e38f;
    float mx = sj;
#pragma unroll
    for (int off = 32; off >= 1; off >>= 1) mx = fmaxf(mx, __shfl_xor(mx, off));
    float e = (lane < c) ? __expf(sj - mx) : 0.0f;
    float ssum = e;
#pragma unroll
    for (int off = 32; off >= 1; off >>= 1) ssum += __shfl_xor(ssum, off);
    if (lane < c) sp[h][lane] = e / ssum;
    __syncthreads();
    float acc = 0.0f;
    for (int j = 0; j < c; ++j) {
        int col = sc[j];
        acc += sp[h][j] * (float)vg[(kvBase + col) * 256 + h * 64 + lane];
    }
    og[qoff] = (bf16)acc;
}

// ---------------- launcher ----------------
extern "C" void kernel_launch(void* const* d_in, const int* in_sizes, int n_in,
                              void* d_out, int out_size, void* d_ws, size_t ws_size,
                              hipStream_t stream)
{
    const float* x   = (const float*)d_in[0];
    const float* L   = (const float*)d_in[1];
    const float* adj = (const float*)d_in[2];
    const float* Wc  = (const float*)d_in[3];
    const float* bc  = (const float*)d_in[4];
    const float* g1  = (const float*)d_in[5];
    const float* be1 = (const float*)d_in[6];
    const float* Wq  = (const float*)d_in[7];
    const float* Wk  = (const float*)d_in[8];
    const float* Wv  = (const float*)d_in[9];
    const float* Wo  = (const float*)d_in[10];
    const float* bo  = (const float*)d_in[11];
    const float* g2  = (const float*)d_in[12];
    const float* be2 = (const float*)d_in[13];
    const float* W1  = (const float*)d_in[14];
    const float* b1  = (const float*)d_in[15];
    const float* W2  = (const float*)d_in[16];
    const float* b2  = (const float*)d_in[17];
    const float* g3  = (const float*)d_in[18];
    const float* be3 = (const float*)d_in[19];
    float* out = (float*)d_out;

    char* ws = (char*)d_ws;
    size_t off = 0;
    auto alloc = [&](size_t bytes) -> void* {
        void* p = ws + off;
        off = (off + bytes + 255) & ~(size_t)255;
        return p;
    };
    float* lam           = (float*)alloc(256);
    int* cnt             = (int*)alloc(2048 * 4);
    unsigned short* cols = (unsigned short*)alloc(2048 * 64 * 2);
    bf16* WcT = (bf16*)alloc(65536 * 2);
    bf16* WqT = (bf16*)alloc(65536 * 2);   // WqT,WkT,WvT contiguous (btZ = 65536)
    bf16* WkT = (bf16*)alloc(65536 * 2);
    bf16* WvT = (bf16*)alloc(65536 * 2);
    bf16* WoT = (bf16*)alloc(65536 * 2);
    bf16* W1T = (bf16*)alloc(131072 * 2);
    bf16* W2T = (bf16*)alloc(131072 * 2);
    bf16* Lb  = (bf16*)alloc((size_t)2048 * 2048 * 2);
    bf16* xT  = (bf16*)alloc((size_t)4 * 256 * 2048 * 2);
    float* xp0f = (float*)alloc((size_t)2 * 8192 * 256 * 4);   // split-K fp32 partials
    float* x1f = (float*)alloc((size_t)8192 * 256 * 4);
    bf16* x1b  = (bf16*)alloc((size_t)8192 * 256 * 2);
    bf16* qb   = (bf16*)alloc((size_t)3 * 8192 * 256 * 2);
    bf16* ob   = (bf16*)alloc((size_t)8192 * 256 * 2);
    float* x2f = (float*)alloc((size_t)8192 * 256 * 4);
    bf16* x2b  = (bf16*)alloc((size_t)8192 * 256 * 2);
    bf16* m1   = (bf16*)alloc((size_t)8192 * 512 * 2);
    (void)in_sizes; (void)n_in; (void)out_size; (void)ws_size;

    dim3 blk(256);
    // transposes + CSR + Lb, one launch
    k_pre<<<dim3(16, 64, 16), blk, 0, stream>>>(Wc, Wq, Wk, Wv, Wo, W1, W2, x, adj,
                                                WcT, WqT, WkT, WvT, WoT, W1T, W2T, xT, cnt, cols,
                                                L, Lb);
    // block 0: Lanczos -> lam ; blocks 1..256: split-K2 partials of L @ x (lam-free)
    k_main<<<dim3(257), dim3(1024), 0, stream>>>(cnt, cols, lam, Lb, xT, xp0f);
    // x1 = relu(LN((s2*(pa+pb) - x)@Wc + bc; g1,be1)) + x
    k_gemm<2, 1><<<dim3(128, 1, 1), blk, 0, stream>>>(
        nullptr, xp0f, xp0f + (size_t)8192 * 256, x, WcT, x1f, x1b, bc, x, g1, be1, lam,
        256, 0L, 0L, 0L, 256);
    // q,k,v = x1 @ {Wq,Wk,Wv}
    k_gemm<1, 0><<<dim3(128, 1, 3), blk, 0, stream>>>(
        x1b, nullptr, nullptr, nullptr, WqT, nullptr, qb, nullptr, nullptr, nullptr, nullptr, nullptr,
        256, 0L, 65536L, 8192L, 256);
    // sparse masked attention
    bf16* kb  = qb + (size_t)8192 * 256;
    bf16* vb2 = qb + (size_t)2 * 8192 * 256;
    k_attn<<<dim3(8192), blk, 0, stream>>>(qb, kb, vb2, ob, cnt, cols);
    // x2 = LN(x1 + o@Wo + bo; g2,be2)
    k_gemm<1, 2><<<dim3(128, 1, 1), blk, 0, stream>>>(
        ob, nullptr, nullptr, nullptr, WoT, x2f, x2b, bo, x1f, g2, be2, nullptr,
        256, 0L, 0L, 0L, 256);
    // m1 = gelu(x2@W1 + b1)
    k_gemm<1, 3><<<dim3(128, 2, 1), blk, 0, stream>>>(
        x2b, nullptr, nullptr, nullptr, W1T, nullptr, m1, b1, nullptr, nullptr, nullptr, nullptr,
        256, 0L, 0L, 0L, 512);
    // out = LN(x2 + m1@W2 + b2; g3,be3)
    k_gemm<1, 2><<<dim3(128, 1, 1), blk, 0, stream>>>(
        m1, nullptr, nullptr, nullptr, W2T, out, nullptr, b2, x2f, g3, be3, nullptr,
        512, 0L, 0L, 0L, 256);
}